// Round 5
// baseline (4653.013 us; speedup 1.0000x reference)
//
#include <hip/hip_runtime.h>
#include <hip/hip_bf16.h>

// Collapsed algebra:
//   out[i] = s * (A^12 x)[i] + t * (A^11 1)[i] + b11
// where A = D^{-1/2} (W + I) D^{-1/2} (self loops weight 1),
//   v = O_0 (O_1 (... (O_9 W11))),  O_k = Taylor_10(expm(Wk - Wk^T))
//   s = W0 . v,  t = b0 . v
//
// R1: scatter-atomics -> CSR gathers.  R2: ticket+u-space.  R3/R4: bin-gather.
// R5: ONE cooperative kernel. 782 bins (256 nodes) <-> 782 blocks + 1 v_chain
//     block. Build with no global atomics: LDS hist -> H[bin][block] matrix ->
//     per-row scan -> bin scan -> LDS-ranked placement. 12 gather iterations
//     separated by manual device-scope grid barriers (no launch gaps).

#define TPB 256
#define MAXBIN 1024

// ---------------- grid barrier (device-scope, sense via generation) ---------
__device__ __forceinline__ void gsync(int* cnt, int* gen, int nb) {
    __threadfence();
    __syncthreads();
    if (threadIdx.x == 0) {
        int g = __hip_atomic_load(gen, __ATOMIC_RELAXED, __HIP_MEMORY_SCOPE_AGENT);
        int a = __hip_atomic_fetch_add(cnt, 1, __ATOMIC_ACQ_REL, __HIP_MEMORY_SCOPE_AGENT);
        if (a == nb - 1) {
            __hip_atomic_store(cnt, 0, __ATOMIC_RELEASE, __HIP_MEMORY_SCOPE_AGENT);
            __hip_atomic_fetch_add(gen, 1, __ATOMIC_ACQ_REL, __HIP_MEMORY_SCOPE_AGENT);
        } else {
            while (__hip_atomic_load(gen, __ATOMIC_ACQUIRE, __HIP_MEMORY_SCOPE_AGENT) == g)
                __builtin_amdgcn_s_sleep(2);
        }
    }
    __syncthreads();
    __threadfence();
}

// ---------------- 1024-entry exclusive scan (256 threads, 4/thread) ---------
__device__ __forceinline__ int scan_excl(int* s, int* ps, int t) {
    int b4 = t * 4;
    int h0 = s[b4], h1 = s[b4 + 1], h2 = s[b4 + 2], h3 = s[b4 + 3];
    int s1 = h0 + h1, s2 = s1 + h2, tot = s2 + h3;
    ps[t] = tot;
    __syncthreads();
    for (int o = 1; o < TPB; o <<= 1) {
        int u = (t >= o) ? ps[t - o] : 0;
        __syncthreads();
        ps[t] += u;
        __syncthreads();
    }
    int eb = ps[t] - tot;
    s[b4] = eb; s[b4 + 1] = eb + h0; s[b4 + 2] = eb + s1; s[b4 + 3] = eb + s2;
    int total = ps[TPB - 1];
    __syncthreads();
    return total;
}

// ---------------- v-chain: 100 sequential 64x64 matvecs, one block ----------
__device__ void v_chain(const float* __restrict__ W_orth,
                        const float* __restrict__ W11,
                        const float* __restrict__ W0,
                        const float* __restrict__ b0,
                        float* __restrict__ scal) {
    __shared__ float S[64 * 65];
    __shared__ float uvec[64];
    __shared__ float term[64];
    __shared__ float accv[64];
    const int tid = threadIdx.x;

    if (tid < 64) uvec[tid] = W11[tid];
    __syncthreads();

    for (int k = 9; k >= 0; --k) {
        const float* Wk = W_orth + k * 4096;
        for (int e = tid; e < 4096; e += TPB) {
            int i = e >> 6, j = e & 63;
            S[i * 65 + j] = Wk[i * 64 + j] - Wk[j * 64 + i];
        }
        __syncthreads();
        if (tid < 64) { term[tid] = uvec[tid]; accv[tid] = uvec[tid]; }
        __syncthreads();
        for (int t = 1; t <= 10; ++t) {
            const int r = tid >> 2, q = tid & 3;
            const int jb = q * 16;
            float p = 0.f;
            #pragma unroll
            for (int jj = 0; jj < 16; ++jj)
                p += S[r * 65 + jb + jj] * term[jb + jj];
            p += __shfl_xor(p, 1);
            p += __shfl_xor(p, 2);
            __syncthreads();
            if (q == 0) {
                float nt = p / (float)t;
                term[r] = nt;
                accv[r] += nt;
            }
            __syncthreads();
        }
        if (tid < 64) uvec[tid] = accv[tid];
        __syncthreads();
    }
    if (tid < 64) {
        float a = W0[tid] * uvec[tid];
        float b = b0[tid] * uvec[tid];
        #pragma unroll
        for (int off = 32; off; off >>= 1) {
            a += __shfl_down(a, off);
            b += __shfl_down(b, off);
        }
        if (tid == 0) { scal[0] = a; scal[1] = b; }
    }
}

// ---------------- the fused kernel ------------------------------------------
__global__ __launch_bounds__(TPB, 4) void fused(
        const float* __restrict__ x, const int* __restrict__ ei,
        const float* __restrict__ w,
        const float* __restrict__ W0, const float* __restrict__ b0,
        const float* __restrict__ W_orth, const float* __restrict__ W11,
        const float* __restrict__ b11,
        float2* __restrict__ uA, float2* __restrict__ uB,
        int2* __restrict__ rec, int* __restrict__ H,
        int* __restrict__ binCnt, int* __restrict__ binOff,
        float* __restrict__ dis, float* __restrict__ d2,
        float* __restrict__ scal, int* __restrict__ bar,
        float* __restrict__ out,
        int N, int E, int nbin, int epb) {
    const int me = blockIdx.x, t = threadIdx.x;
    const int nblocks = (int)gridDim.x;          // nbin + 1
    int* cnt = bar;
    int* gen = bar + 1;

    __shared__ int hist[MAXBIN];
    __shared__ int sbuf[MAXBIN];
    __shared__ int psum[TPB];
    __shared__ float accx[TPB];
    __shared__ float accy[TPB];

    // ---- P0: per-chunk histogram -> H[bin][block]; extra block: v_chain ----
    if (me == nbin) {
        v_chain(W_orth, W11, W0, b0, scal);
    } else {
        for (int b = t; b < nbin; b += TPB) hist[b] = 0;
        __syncthreads();
        int e0 = me * epb, e1 = min(E, e0 + epb);
        for (int e = e0 + t; e < e1; e += TPB)
            atomicAdd(&hist[ei[E + e] >> 8], 1);
        __syncthreads();
        for (int b = t; b < nbin; b += TPB) H[b * nbin + me] = hist[b];
    }
    gsync(cnt, gen, nblocks);

    // ---- P1: scan row `me` of H (prefix over blocks); binCnt[me] = total ---
    if (me < nbin) {
        int base = me * nbin;
        int b4 = t * 4;
        #pragma unroll
        for (int q = 0; q < 4; ++q)
            sbuf[b4 + q] = (b4 + q < nbin) ? H[base + b4 + q] : 0;
        __syncthreads();
        int tot = scan_excl(sbuf, psum, t);
        #pragma unroll
        for (int q = 0; q < 4; ++q)
            if (b4 + q < nbin) H[base + b4 + q] = sbuf[b4 + q];
        if (t == 0) binCnt[me] = tot;
    }
    gsync(cnt, gen, nblocks);

    // ---- P2: block 0 scans binCnt -> binOff ------------------------------
    if (me == 0) {
        int b4 = t * 4;
        #pragma unroll
        for (int q = 0; q < 4; ++q)
            sbuf[b4 + q] = (b4 + q < nbin) ? binCnt[b4 + q] : 0;
        __syncthreads();
        int tot = scan_excl(sbuf, psum, t);
        #pragma unroll
        for (int q = 0; q < 4; ++q)
            if (b4 + q < nbin) binOff[b4 + q] = sbuf[b4 + q];
        if (t == 0) binOff[nbin] = tot;
    }
    gsync(cnt, gen, nblocks);

    // ---- P3: place records (LDS rank atomics only) ------------------------
    if (me < nbin) {
        for (int b = t; b < nbin; b += TPB) hist[b] = 0;
        __syncthreads();
        int e0 = me * epb, e1 = min(E, e0 + epb);
        for (int e = e0 + t; e < e1; e += TPB) {
            int src = ei[e], c = ei[E + e];
            float wv = w[e];
            int b = c >> 8;
            int r = atomicAdd(&hist[b], 1);
            int p = binOff[b] + H[b * nbin + me] + r;
            rec[p] = make_int2(src | ((c & 255) << 18), __float_as_int(wv));
        }
    }
    gsync(cnt, gen, nblocks);

    // ---- P4: degree + u0 = dis .* [x, 1] ----------------------------------
    if (me < nbin) {
        accx[t] = 0.f;
        __syncthreads();
        int k0 = binOff[me], k1 = binOff[me + 1];
        for (int k = k0 + t; k < k1; k += TPB) {
            int2 rc = rec[k];
            atomicAdd(&accx[rc.x >> 18], __int_as_float(rc.y));
        }
        __syncthreads();
        int i = (me << 8) + t;
        if (i < N) {
            float deg = 1.0f + accx[t];
            float ds = rsqrtf(deg);
            dis[i] = ds;
            d2[i]  = 1.0f / deg;
            uA[i] = make_float2(ds * x[i], ds);
        }
    }
    gsync(cnt, gen, nblocks);

    // ---- P5: 12 propagation iterations ------------------------------------
    for (int it = 0; it < 12; ++it) {
        const float2* pv = (it & 1) ? uB : uA;
        float2*       cv = (it & 1) ? uA : uB;
        if (me < nbin) {
            accx[t] = 0.f;
            accy[t] = 0.f;
            __syncthreads();
            int k0 = binOff[me], k1 = binOff[me + 1];
            for (int k = k0 + t; k < k1; k += TPB) {
                int2 rc = rec[k];
                float wv = __int_as_float(rc.y);
                float2 uv = pv[rc.x & 0x3FFFF];
                int cl = rc.x >> 18;
                atomicAdd(&accx[cl], wv * uv.x);
                atomicAdd(&accy[cl], wv * uv.y);
            }
            __syncthreads();
            int i = (me << 8) + t;
            if (i < N) {
                float2 ui = pv[i];
                float sc = d2[i];
                cv[i] = make_float2(sc * (ui.x + accx[t]), sc * (ui.y + accy[t]));
            }
        }
        if (it < 11) gsync(cnt, gen, nblocks);
        // after it=11: uA = u12, uB = u11, all same-thread data below
    }

    // ---- P6: out = (s*u12.x + t*u11.y)/dis + b11 (same-thread data) -------
    if (me < nbin) {
        int i = (me << 8) + t;
        if (i < N)
            out[i] = (scal[0] * uA[i].x + scal[1] * uB[i].y) / dis[i] + b11[0];
    }
}

// ---------------- launch ----------------------------------------------------
extern "C" void kernel_launch(void* const* d_in, const int* in_sizes, int n_in,
                              void* d_out, int out_size, void* d_ws, size_t ws_size,
                              hipStream_t stream) {
    const float* x      = (const float*)d_in[0];
    const int*   ei     = (const int*)d_in[1];
    const float* w      = (const float*)d_in[2];
    const float* W0     = (const float*)d_in[3];
    const float* b0     = (const float*)d_in[4];
    const float* W_orth = (const float*)d_in[5];
    const float* W11    = (const float*)d_in[6];
    const float* b11    = (const float*)d_in[7];

    const int N = in_sizes[0];          // 200000
    const int E = in_sizes[2];          // 1200000
    const int nbin = (N + 255) >> 8;    // 782 (requires N < 2^18 for packing)
    const int epb = (E + nbin - 1) / nbin;

    // workspace layout (8B-aligned first)
    char* ws = (char*)d_ws;
    float2* uA     = (float2*)ws;  ws += (size_t)N * 8;
    float2* uB     = (float2*)ws;  ws += (size_t)N * 8;
    int2*   rec    = (int2*)ws;    ws += (size_t)E * 8;
    int*    H      = (int*)ws;     ws += (size_t)nbin * nbin * 4;
    int*    binCnt = (int*)ws;     ws += MAXBIN * 4;
    int*    binOff = (int*)ws;     ws += (MAXBIN + 1) * 4;
    float*  dis    = (float*)ws;   ws += (size_t)N * 4;
    float*  d2     = (float*)ws;   ws += (size_t)N * 4;
    float*  scal   = (float*)ws;   ws += 16;
    int*    bar    = (int*)ws;     ws += 16;

    hipMemsetAsync(bar, 0, 16, stream);

    float* outp = (float*)d_out;
    int Na = N, Ea = E, nbina = nbin, epba = epb;
    void* args[] = {(void*)&x, (void*)&ei, (void*)&w, (void*)&W0, (void*)&b0,
                    (void*)&W_orth, (void*)&W11, (void*)&b11,
                    (void*)&uA, (void*)&uB, (void*)&rec, (void*)&H,
                    (void*)&binCnt, (void*)&binOff, (void*)&dis, (void*)&d2,
                    (void*)&scal, (void*)&bar, (void*)&outp,
                    (void*)&Na, (void*)&Ea, (void*)&nbina, (void*)&epba};
    hipLaunchCooperativeKernel((void*)fused, dim3(nbin + 1), dim3(TPB),
                               args, 0, stream);
}

// Round 6
// 482.605 us; speedup vs baseline: 9.6415x; 9.6415x over previous
//
#include <hip/hip_runtime.h>
#include <hip/hip_bf16.h>

// Collapsed algebra:
//   out[i] = s * (A^12 x)[i] + t * (A^11 1)[i] + b11
// where A = D^{-1/2} (W + I) D^{-1/2} (self loops weight 1),
//   v = O_0 (O_1 (... (O_9 W11))),  O_k = Taylor_10(expm(Wk - Wk^T))
//   s = W0 . v,  t = b0 . v
//
// R6: multi-kernel (coop-kernel agent fences nuke per-XCD L2 -> 4.6ms, R5).
//  - Build with ZERO global atomics: H[chunk][bin] histogram matrix,
//    per-bin row scan, bin scan, LDS-ranked placement.
//  - 128-node bins -> 1563 blocks per gather (75% occupancy).
//  - v_chain single-wave (no barriers), split across k_hist / k_place.
//  - final output fused into 12th gather.

#define TPB 256
#define NCHUNK 512          // edge chunks (= 2*TPB, k_scanrow assumes this)
#define MAXBIN 2048         // supports N <= 262144 at 128 nodes/bin
#define BSH 7               // 128 nodes per bin
#define BSZ 128

// ---------------- v-chain half: single wave, no __syncthreads --------------
// st: scal buffer; st[0]=s, st[1]=t, st[2..66) = carried 64-vector state
__device__ void v_part(const float* __restrict__ W_orth,
                       const float* __restrict__ W11,
                       const float* __restrict__ W0,
                       const float* __restrict__ b0,
                       float* __restrict__ st,
                       int khi, int klo, bool first) {
    const int l = threadIdx.x;
    if (l >= 64) return;                       // single wave does all work
    __shared__ float S[64 * 65];               // +1 pad: conflict-free rows
    __shared__ float Wl[4096];
    __shared__ float tl[64];
    float u = first ? W11[l] : st[2 + l];
    for (int k = khi; k >= klo; --k) {
        const float* Wk = W_orth + (size_t)k * 4096;
        #pragma unroll 1
        for (int i = 0; i < 64; ++i) Wl[i * 64 + l] = Wk[i * 64 + l];
        // same-wave DS ops execute in order; cross-lane reads below are safe
        #pragma unroll 1
        for (int i = 0; i < 64; ++i) S[i * 65 + l] = Wl[i * 64 + l] - Wl[l * 64 + i];
        float term = u, acc = u;
        for (int t = 1; t <= 10; ++t) {
            tl[l] = term;
            float p = 0.f;
            #pragma unroll 16
            for (int j = 0; j < 64; ++j)
                p = fmaf(S[l * 65 + j], tl[j], p);   // tl[j]: LDS broadcast
            term = p / (float)t;
            acc += term;
        }
        u = acc;
    }
    if (klo == 0) {
        float a = W0[l] * u, b = b0[l] * u;
        #pragma unroll
        for (int off = 32; off; off >>= 1) {
            a += __shfl_down(a, off);
            b += __shfl_down(b, off);
        }
        if (l == 0) { st[0] = a; st[1] = b; }
    } else {
        st[2 + l] = u;
    }
}

// ---------------- build kernels --------------------------------------------
// per-chunk histogram -> H[chunk][bin] (coalesced dump). Extra block: vchain A
__global__ void k_hist(const int* __restrict__ ei, int E, int nbin, int epb,
                       int* __restrict__ H,
                       const float* __restrict__ W_orth,
                       const float* __restrict__ W11, float* __restrict__ scal) {
    const int me = blockIdx.x, t = threadIdx.x;
    if (me == NCHUNK) { v_part(W_orth, W11, nullptr, nullptr, scal, 9, 5, true); return; }
    __shared__ int hist[MAXBIN];
    for (int b = t; b < nbin; b += TPB) hist[b] = 0;
    __syncthreads();
    const int e0 = me * epb, e1 = min(E, e0 + epb);
    for (int e = e0 + t; e < e1; e += TPB)
        atomicAdd(&hist[ei[E + e] >> BSH], 1);
    __syncthreads();
    const int base = me * nbin;
    for (int b = t; b < nbin; b += TPB) H[base + b] = hist[b];
}

// per-bin: exclusive scan of H[:,b] over 512 chunks; binCnt[b] = total
__global__ void k_scanrow(int* __restrict__ H, int* __restrict__ binCnt, int nbin) {
    const int b = blockIdx.x, t = threadIdx.x;
    __shared__ int ps[TPB];
    const int i0 = (2 * t) * nbin + b, i1 = (2 * t + 1) * nbin + b;
    int v0 = H[i0], v1 = H[i1];
    int pair = v0 + v1;
    ps[t] = pair;
    __syncthreads();
    for (int o = 1; o < TPB; o <<= 1) {
        int u = (t >= o) ? ps[t - o] : 0;
        __syncthreads();
        ps[t] += u;
        __syncthreads();
    }
    int excl = ps[t] - pair;
    H[i0] = excl;
    H[i1] = excl + v0;
    if (t == TPB - 1) binCnt[b] = ps[t];
}

// one block: exclusive scan binCnt -> binOff
__global__ void k_scanbin(const int* __restrict__ binCnt, int* __restrict__ binOff,
                          int nbin) {
    __shared__ int sb[TPB];
    const int t = threadIdx.x;
    int carry = 0;
    for (int base = 0; base < nbin; base += TPB) {
        int idx = base + t;
        int v = (idx < nbin) ? binCnt[idx] : 0;
        sb[t] = v;
        __syncthreads();
        for (int o = 1; o < TPB; o <<= 1) {
            int u = (t >= o) ? sb[t - o] : 0;
            __syncthreads();
            sb[t] += u;
            __syncthreads();
        }
        if (idx < nbin) binOff[idx] = carry + sb[t] - v;
        carry += sb[TPB - 1];
        __syncthreads();
    }
    if (t == 0) binOff[nbin] = carry;
}

// placement: LDS rank atomics only. Extra block: vchain B + dots.
__global__ void k_place(const int* __restrict__ ei, const float* __restrict__ w,
                        int E, int nbin, int epb,
                        const int* __restrict__ H, const int* __restrict__ binOff,
                        int2* __restrict__ rec,
                        const float* __restrict__ W_orth,
                        const float* __restrict__ W0, const float* __restrict__ b0,
                        float* __restrict__ scal) {
    const int me = blockIdx.x, t = threadIdx.x;
    if (me == NCHUNK) { v_part(W_orth, nullptr, W0, b0, scal, 4, 0, false); return; }
    __shared__ int hrow[MAXBIN];
    __shared__ int rank[MAXBIN];
    for (int b = t; b < nbin; b += TPB) {
        hrow[b] = binOff[b] + H[me * nbin + b];
        rank[b] = 0;
    }
    __syncthreads();
    const int e0 = me * epb, e1 = min(E, e0 + epb);
    for (int e = e0 + t; e < e1; e += TPB) {
        int src = ei[e], c = ei[E + e];
        float wv = w[e];
        int b = c >> BSH;
        int r = atomicAdd(&rank[b], 1);
        rec[hrow[b] + r] = make_int2(src | ((c & (BSZ - 1)) << 18),
                                     __float_as_int(wv));
    }
}

// per-bin degree + u0 = dis .* [x, 1]
__global__ void k_deg(const int* __restrict__ binOff, const int2* __restrict__ rec,
                      const float* __restrict__ x, float* __restrict__ dis,
                      float* __restrict__ d2, float2* __restrict__ u, int N) {
    const int b = blockIdx.x, t = threadIdx.x;
    __shared__ float dacc[BSZ];
    if (t < BSZ) dacc[t] = 0.f;
    __syncthreads();
    const int k0 = binOff[b], k1 = binOff[b + 1];
    for (int k = k0 + t; k < k1; k += TPB) {
        int2 rc = rec[k];
        atomicAdd(&dacc[rc.x >> 18], __int_as_float(rc.y));
    }
    __syncthreads();
    if (t < BSZ) {
        int i = (b << BSH) + t;
        if (i < N) {
            float deg = 1.0f + dacc[t];
            float ds = rsqrtf(deg);
            dis[i] = ds;
            d2[i] = 1.0f / deg;
            u[i] = make_float2(ds * x[i], ds);
        }
    }
}

// one propagation in u-space; final==1 fuses the output epilogue
__global__ void k_gather(const int* __restrict__ binOff, const int2* __restrict__ rec,
                         const float* __restrict__ d2,
                         const float2* __restrict__ pv, float2* __restrict__ cv,
                         int N, int final,
                         const float* __restrict__ scal,
                         const float* __restrict__ dis,
                         const float* __restrict__ b11, float* __restrict__ out) {
    const int b = blockIdx.x, t = threadIdx.x;
    __shared__ float accx[BSZ];
    __shared__ float accy[BSZ];
    if (t < BSZ) { accx[t] = 0.f; accy[t] = 0.f; }
    __syncthreads();
    const int k0 = binOff[b], k1 = binOff[b + 1];
    for (int k = k0 + t; k < k1; k += TPB) {
        int2 rc = rec[k];
        float wv = __int_as_float(rc.y);
        float2 uv = pv[rc.x & 0x3FFFF];
        int cl = rc.x >> 18;
        atomicAdd(&accx[cl], wv * uv.x);
        atomicAdd(&accy[cl], wv * uv.y);
    }
    __syncthreads();
    if (t < BSZ) {
        int i = (b << BSH) + t;
        if (i < N) {
            float2 ui = pv[i];            // iteration-11 state = u11
            float sc = d2[i];
            float nx = sc * (ui.x + accx[t]);   // u12.x
            if (final)
                out[i] = (scal[0] * nx + scal[1] * ui.y) / dis[i] + b11[0];
            else
                cv[i] = make_float2(nx, sc * (ui.y + accy[t]));
        }
    }
}

// ---------------- launch ----------------------------------------------------
extern "C" void kernel_launch(void* const* d_in, const int* in_sizes, int n_in,
                              void* d_out, int out_size, void* d_ws, size_t ws_size,
                              hipStream_t stream) {
    const float* x      = (const float*)d_in[0];
    const int*   ei     = (const int*)d_in[1];
    const float* w      = (const float*)d_in[2];
    const float* W0     = (const float*)d_in[3];
    const float* b0     = (const float*)d_in[4];
    const float* W_orth = (const float*)d_in[5];
    const float* W11    = (const float*)d_in[6];
    const float* b11    = (const float*)d_in[7];

    const int N = in_sizes[0];              // 200000
    const int E = in_sizes[2];              // 1200000
    const int nbin = (N + BSZ - 1) >> BSH;  // 1563
    const int epb  = (E + NCHUNK - 1) / NCHUNK;

    // workspace layout (8B-aligned first)
    char* ws = (char*)d_ws;
    float2* uA     = (float2*)ws;  ws += (size_t)N * 8;
    float2* uB     = (float2*)ws;  ws += (size_t)N * 8;
    int2*   rec    = (int2*)ws;    ws += (size_t)E * 8;
    int*    H      = (int*)ws;     ws += (size_t)NCHUNK * nbin * 4;
    int*    binCnt = (int*)ws;     ws += (size_t)nbin * 4;
    int*    binOff = (int*)ws;     ws += (size_t)(nbin + 1) * 4;
    float*  dis    = (float*)ws;   ws += (size_t)N * 4;
    float*  d2     = (float*)ws;   ws += (size_t)N * 4;
    float*  scal   = (float*)ws;   ws += 80 * 4;

    k_hist<<<NCHUNK + 1, TPB, 0, stream>>>(ei, E, nbin, epb, H, W_orth, W11, scal);
    k_scanrow<<<nbin, TPB, 0, stream>>>(H, binCnt, nbin);
    k_scanbin<<<1, TPB, 0, stream>>>(binCnt, binOff, nbin);
    k_place<<<NCHUNK + 1, TPB, 0, stream>>>(ei, w, E, nbin, epb, H, binOff, rec,
                                            W_orth, W0, b0, scal);
    k_deg<<<nbin, TPB, 0, stream>>>(binOff, rec, x, dis, d2, uA, N);

    float2* prev = uA;
    float2* cur  = uB;
    for (int it = 0; it < 12; ++it) {
        k_gather<<<nbin, TPB, 0, stream>>>(binOff, rec, d2, prev, cur, N,
                                           it == 11 ? 1 : 0, scal, dis, b11,
                                           (float*)d_out);
        float2* tmp = prev; prev = cur; cur = tmp;
    }
}

// Round 7
// 338.989 us; speedup vs baseline: 13.7261x; 1.4237x over previous
//
#include <hip/hip_runtime.h>
#include <hip/hip_bf16.h>

// Collapsed algebra:
//   out[i] = s * (A^12 x)[i] + t * (A^11 1)[i] + b11
//          = (A^11 (s * A x + t * 1))[i] + b11          <- single channel!
// where A = D^{-1/2} (W + I) D^{-1/2} (self loops weight 1),
//   v = O_0 (O_1 (... (O_9 W11))),  O_k = Taylor_10(expm(Wk - Wk^T))
//   s = W0 . v,  t = b0 . v
// u-space: u = dis .* y  =>  u' = d2 .* (u + sum_e w_e u_src)
//
// R7: (1) single-channel propagation (combine s,t after first hop);
//     (2) LDS union of v_chain scratch with build arrays (49.6KB -> 17KB,
//         8 blocks/CU) to hide the scattered rec-write latency.

#define TPB 256
#define NCHUNK 512          // edge chunks (k_scanrow assumes = 2*TPB)
#define MAXBIN 2048         // supports N <= 262144 at 128 nodes/bin
#define BSH 7               // 128 nodes per bin
#define BSZ 128
#define SMEMF 4224          // floats: S[64*65] + tl[64] = 4160 + 64

// ---------------- v-chain half: single wave, no __syncthreads --------------
// smem: >= SMEMF floats. st: st[0]=s, st[1]=t, st[2..66) carried state.
__device__ void v_part(float* __restrict__ smem,
                       const float* __restrict__ W_orth,
                       const float* __restrict__ W11,
                       const float* __restrict__ W0,
                       const float* __restrict__ b0,
                       float* __restrict__ st,
                       int khi, int klo, bool first) {
    const int l = threadIdx.x;
    if (l >= 64) return;                       // single wave
    float* S  = smem;                          // [64*65], +1 pad per row
    float* tl = smem + 4160;                   // [64]
    float u = first ? W11[l] : st[2 + l];
    for (int k = khi; k >= klo; --k) {
        const float* Wk = W_orth + (size_t)k * 4096;
        #pragma unroll 1
        for (int i = 0; i < 64; ++i)
            S[i * 65 + l] = Wk[i * 64 + l] - Wk[l * 64 + i];
        float term = u, acc = u;
        for (int t = 1; t <= 10; ++t) {
            tl[l] = term;
            float p = 0.f;
            #pragma unroll 16
            for (int j = 0; j < 64; ++j)
                p = fmaf(S[l * 65 + j], tl[j], p);   // tl[j]: LDS broadcast
            term = p / (float)t;
            acc += term;
        }
        u = acc;
    }
    if (klo == 0) {
        float a = W0[l] * u, b = b0[l] * u;
        #pragma unroll
        for (int off = 32; off; off >>= 1) {
            a += __shfl_down(a, off);
            b += __shfl_down(b, off);
        }
        if (l == 0) { st[0] = a; st[1] = b; }
    } else {
        st[2 + l] = u;
    }
}

// ---------------- build kernels --------------------------------------------
// per-chunk histogram -> H[chunk][bin]. Extra block: vchain layers 9..5.
__global__ __launch_bounds__(TPB) void k_hist(
        const int* __restrict__ ei, int E, int nbin, int epb,
        int* __restrict__ H,
        const float* __restrict__ W_orth,
        const float* __restrict__ W11, float* __restrict__ scal) {
    __shared__ float smem[SMEMF];
    const int me = blockIdx.x, t = threadIdx.x;
    if (me == NCHUNK) { v_part(smem, W_orth, W11, nullptr, nullptr, scal, 9, 5, true); return; }
    int* hist = (int*)smem;                    // [MAXBIN] <= 8KB
    for (int b = t; b < nbin; b += TPB) hist[b] = 0;
    __syncthreads();
    const int e0 = me * epb, e1 = min(E, e0 + epb);
    for (int e = e0 + t; e < e1; e += TPB)
        atomicAdd(&hist[ei[E + e] >> BSH], 1);
    __syncthreads();
    const int base = me * nbin;
    for (int b = t; b < nbin; b += TPB) H[base + b] = hist[b];
}

// per-bin: exclusive scan of H[:,b] over NCHUNK chunks; binCnt[b] = total
__global__ void k_scanrow(int* __restrict__ H, int* __restrict__ binCnt, int nbin) {
    const int b = blockIdx.x, t = threadIdx.x;
    __shared__ int ps[TPB];
    const int i0 = (2 * t) * nbin + b, i1 = (2 * t + 1) * nbin + b;
    int v0 = H[i0], v1 = H[i1];
    int pair = v0 + v1;
    ps[t] = pair;
    __syncthreads();
    for (int o = 1; o < TPB; o <<= 1) {
        int u = (t >= o) ? ps[t - o] : 0;
        __syncthreads();
        ps[t] += u;
        __syncthreads();
    }
    int excl = ps[t] - pair;
    H[i0] = excl;
    H[i1] = excl + v0;
    if (t == TPB - 1) binCnt[b] = ps[t];
}

// one block: exclusive scan binCnt -> binOff
__global__ void k_scanbin(const int* __restrict__ binCnt, int* __restrict__ binOff,
                          int nbin) {
    __shared__ int sb[TPB];
    const int t = threadIdx.x;
    int carry = 0;
    for (int base = 0; base < nbin; base += TPB) {
        int idx = base + t;
        int v = (idx < nbin) ? binCnt[idx] : 0;
        sb[t] = v;
        __syncthreads();
        for (int o = 1; o < TPB; o <<= 1) {
            int u = (t >= o) ? sb[t - o] : 0;
            __syncthreads();
            sb[t] += u;
            __syncthreads();
        }
        if (idx < nbin) binOff[idx] = carry + sb[t] - v;
        carry += sb[TPB - 1];
        __syncthreads();
    }
    if (t == 0) binOff[nbin] = carry;
}

// placement: LDS rank atomics only. Extra block: vchain layers 4..0 + dots.
__global__ __launch_bounds__(TPB) void k_place(
        const int* __restrict__ ei, const float* __restrict__ w,
        int E, int nbin, int epb,
        const int* __restrict__ H, const int* __restrict__ binOff,
        int2* __restrict__ rec,
        const float* __restrict__ W_orth,
        const float* __restrict__ W0, const float* __restrict__ b0,
        float* __restrict__ scal) {
    __shared__ float smem[SMEMF];
    const int me = blockIdx.x, t = threadIdx.x;
    if (me == NCHUNK) { v_part(smem, W_orth, nullptr, W0, b0, scal, 4, 0, false); return; }
    int* hrow = (int*)smem;                    // [MAXBIN]
    int* rank = ((int*)smem) + MAXBIN;         // [MAXBIN]  (16KB <= SMEMF*4)
    for (int b = t; b < nbin; b += TPB) {
        hrow[b] = binOff[b] + H[me * nbin + b];
        rank[b] = 0;
    }
    __syncthreads();
    const int e0 = me * epb, e1 = min(E, e0 + epb);
    for (int e = e0 + t; e < e1; e += TPB) {
        int src = ei[e], c = ei[E + e];
        float wv = w[e];
        int b = c >> BSH;
        int r = atomicAdd(&rank[b], 1);
        rec[hrow[b] + r] = make_int2(src | ((c & (BSZ - 1)) << 18),
                                     __float_as_int(wv));
    }
}

// per-bin degree + u0 = dis .* x (single channel)
__global__ void k_deg(const int* __restrict__ binOff, const int2* __restrict__ rec,
                      const float* __restrict__ x, float* __restrict__ dis,
                      float* __restrict__ d2, float* __restrict__ u, int N) {
    const int b = blockIdx.x, t = threadIdx.x;
    __shared__ float dacc[BSZ];
    if (t < BSZ) dacc[t] = 0.f;
    __syncthreads();
    const int k0 = binOff[b], k1 = binOff[b + 1];
    for (int k = k0 + t; k < k1; k += TPB) {
        int2 rc = rec[k];
        atomicAdd(&dacc[rc.x >> 18], __int_as_float(rc.y));
    }
    __syncthreads();
    if (t < BSZ) {
        int i = (b << BSH) + t;
        if (i < N) {
            float deg = 1.0f + dacc[t];
            float ds = rsqrtf(deg);
            dis[i] = ds;
            d2[i] = 1.0f / deg;
            u[i] = ds * x[i];
        }
    }
}

// one single-channel propagation in u-space.
// mode 1: epilogue c = s*u' + t*dis (channel combine after first hop)
// mode 2: epilogue out = u'/dis + b11 (final)
__global__ void k_gather(const int* __restrict__ binOff, const int2* __restrict__ rec,
                         const float* __restrict__ d2,
                         const float* __restrict__ pv, float* __restrict__ cv,
                         int N, int mode,
                         const float* __restrict__ scal,
                         const float* __restrict__ dis,
                         const float* __restrict__ b11, float* __restrict__ out) {
    const int b = blockIdx.x, t = threadIdx.x;
    __shared__ float acc[BSZ];
    if (t < BSZ) acc[t] = 0.f;
    __syncthreads();
    const int k0 = binOff[b], k1 = binOff[b + 1];
    for (int k = k0 + t; k < k1; k += TPB) {
        int2 rc = rec[k];
        atomicAdd(&acc[rc.x >> 18],
                  __int_as_float(rc.y) * pv[rc.x & 0x3FFFF]);
    }
    __syncthreads();
    if (t < BSZ) {
        int i = (b << BSH) + t;
        if (i < N) {
            float up = d2[i] * (pv[i] + acc[t]);
            if (mode == 1)
                cv[i] = scal[0] * up + scal[1] * dis[i];
            else if (mode == 2)
                out[i] = up / dis[i] + b11[0];
            else
                cv[i] = up;
        }
    }
}

// ---------------- launch ----------------------------------------------------
extern "C" void kernel_launch(void* const* d_in, const int* in_sizes, int n_in,
                              void* d_out, int out_size, void* d_ws, size_t ws_size,
                              hipStream_t stream) {
    const float* x      = (const float*)d_in[0];
    const int*   ei     = (const int*)d_in[1];
    const float* w      = (const float*)d_in[2];
    const float* W0     = (const float*)d_in[3];
    const float* b0     = (const float*)d_in[4];
    const float* W_orth = (const float*)d_in[5];
    const float* W11    = (const float*)d_in[6];
    const float* b11    = (const float*)d_in[7];

    const int N = in_sizes[0];              // 200000
    const int E = in_sizes[2];              // 1200000
    const int nbin = (N + BSZ - 1) >> BSH;  // 1563
    const int epb  = (E + NCHUNK - 1) / NCHUNK;

    // workspace layout (8B-aligned first)
    char* ws = (char*)d_ws;
    int2*   rec    = (int2*)ws;    ws += (size_t)E * 8;
    int*    H      = (int*)ws;     ws += (size_t)NCHUNK * nbin * 4;
    float*  uA     = (float*)ws;   ws += (size_t)N * 4;
    float*  uB     = (float*)ws;   ws += (size_t)N * 4;
    int*    binCnt = (int*)ws;     ws += (size_t)nbin * 4;
    int*    binOff = (int*)ws;     ws += (size_t)(nbin + 1) * 4;
    float*  dis    = (float*)ws;   ws += (size_t)N * 4;
    float*  d2     = (float*)ws;   ws += (size_t)N * 4;
    float*  scal   = (float*)ws;   ws += 80 * 4;

    k_hist<<<NCHUNK + 1, TPB, 0, stream>>>(ei, E, nbin, epb, H, W_orth, W11, scal);
    k_scanrow<<<nbin, TPB, 0, stream>>>(H, binCnt, nbin);
    k_scanbin<<<1, TPB, 0, stream>>>(binCnt, binOff, nbin);
    k_place<<<NCHUNK + 1, TPB, 0, stream>>>(ei, w, E, nbin, epb, H, binOff, rec,
                                            W_orth, W0, b0, scal);
    k_deg<<<nbin, TPB, 0, stream>>>(binOff, rec, x, dis, d2, uA, N);

    float* prev = uA;
    float* cur  = uB;
    for (int it = 0; it < 12; ++it) {
        int mode = (it == 0) ? 1 : (it == 11 ? 2 : 0);
        k_gather<<<nbin, TPB, 0, stream>>>(binOff, rec, d2, prev, cur, N,
                                           mode, scal, dis, b11, (float*)d_out);
        float* tmp = prev; prev = cur; cur = tmp;
    }
}

// Round 8
// 323.029 us; speedup vs baseline: 14.4043x; 1.0494x over previous
//
#include <hip/hip_runtime.h>
#include <hip/hip_bf16.h>

// Collapsed algebra:
//   out[i] = s * (A^12 x)[i] + t * (A^11 1)[i] + b11
//          = (A^11 (s * A x + t * 1))[i] + b11          <- single channel
// where A = D^{-1/2} (W + I) D^{-1/2} (self loops weight 1),
//   v = O_0 (O_1 (... (O_9 W11))),  O_k = Taylor_10(expm(Wk - Wk^T))
//   s = W0 . v,  t = b0 . v
// u-space: u = dis .* y  =>  u' = d2 .* (u + sum_e w_e u_src)
//
// R8: two-level radix build. Pass A -> 98 coarse buckets (2048 nodes,
// ~42-record coalesced segments; WRITE amp 3.6x -> ~1.2x). Pass B -> 16
// fine 128-node bins per bucket via LDS batches (fully coalesced), fused
// with degree/dis/d2/u0. v_chain split 6/4 across the two passes.

#define TPB 256
#define CSH 11            // 2048 nodes per coarse bucket
#define CSZ 2048
#define CAPSH 14          // 16384 record slots per bucket (avg fill ~12.2K)
#define FSH 7             // 128 nodes per fine bin
#define FBPB 16           // fine bins per bucket
#define PE 4096           // edges per k_part block

// ---------------- v-chain part: single wave, no __syncthreads --------------
// smem: >= 4224 floats. st: st[0]=s, st[1]=t, st[2..66) carried state.
__device__ void v_part(float* __restrict__ smem,
                       const float* __restrict__ W_orth,
                       const float* __restrict__ W11,
                       const float* __restrict__ W0,
                       const float* __restrict__ b0,
                       float* __restrict__ st,
                       int khi, int klo, bool first) {
    const int l = threadIdx.x;
    if (l >= 64) return;                       // single wave
    float* S  = smem;                          // [64*65], +1 pad per row
    float* tl = smem + 4160;                   // [64]
    float u = first ? W11[l] : st[2 + l];
    for (int k = khi; k >= klo; --k) {
        const float* Wk = W_orth + (size_t)k * 4096;
        #pragma unroll 1
        for (int i = 0; i < 64; ++i)
            S[i * 65 + l] = Wk[i * 64 + l] - Wk[l * 64 + i];
        float term = u, acc = u;
        for (int t = 1; t <= 10; ++t) {
            tl[l] = term;
            float p = 0.f;
            #pragma unroll 16
            for (int j = 0; j < 64; ++j)
                p = fmaf(S[l * 65 + j], tl[j], p);   // tl[j]: LDS broadcast
            term = p / (float)t;
            acc += term;
        }
        u = acc;
    }
    if (klo == 0) {
        float a = W0[l] * u, b = b0[l] * u;
        #pragma unroll
        for (int off = 32; off; off >>= 1) {
            a += __shfl_down(a, off);
            b += __shfl_down(b, off);
        }
        if (l == 0) { st[0] = a; st[1] = b; }
    } else {
        st[2 + l] = u;
    }
}

// ---------------- pass A: edges -> 98 coarse buckets (coalesced) -----------
__global__ __launch_bounds__(TPB) void k_part(
        const int* __restrict__ ei, const float* __restrict__ w,
        int E, int nchunk, int CB,
        int* __restrict__ pos, int2* __restrict__ recA,
        const float* __restrict__ W_orth,
        const float* __restrict__ W11, float* __restrict__ scal) {
    __shared__ float smem[8192];               // staged int2[4096] (32KB)
    __shared__ int hist[128], rank[128], gbase[128];
    __shared__ int sscan[128], starts[129];
    const int me = blockIdx.x, t = threadIdx.x;
    if (me == nchunk) { v_part(smem, W_orth, W11, nullptr, nullptr, scal, 9, 4, true); return; }
    int2* staged = (int2*)smem;
    if (t < 128) { hist[t] = 0; rank[t] = 0; }
    __syncthreads();
    const int e0 = me * PE, e1 = min(E, e0 + PE);
    const int nE = e1 - e0;
    for (int e = e0 + t; e < e1; e += TPB)
        atomicAdd(&hist[ei[E + e] >> CSH], 1);
    __syncthreads();
    if (t < 128) sscan[t] = hist[t];
    __syncthreads();
    for (int o = 1; o < 128; o <<= 1) {
        int v = (t < 128 && t >= o) ? sscan[t - o] : 0;
        __syncthreads();
        if (t < 128) sscan[t] += v;
        __syncthreads();
    }
    if (t < 128) starts[t] = sscan[t] - hist[t];   // exclusive
    if (t == 127) starts[128] = sscan[127];        // = nE
    // reserve global space per touched bucket
    if (t < CB && hist[t] > 0)
        gbase[t] = (t << CAPSH) + atomicAdd(&pos[t], hist[t]);
    __syncthreads();
    // rank + stage (record: src | c_low11 << 18, weight)
    for (int e = e0 + t; e < e1; e += TPB) {
        int src = ei[e], c = ei[E + e];
        float wv = w[e];
        int b = c >> CSH;
        int r = atomicAdd(&rank[b], 1);
        staged[starts[b] + r] = make_int2(src | ((c & (CSZ - 1)) << 18),
                                          __float_as_int(wv));
    }
    __syncthreads();
    // coalesced write-out; bucket via binary search in starts
    for (int s = t; s < nE; s += TPB) {
        int lo = 0, hi = 128;
        while (hi - lo > 1) {
            int mid = (lo + hi) >> 1;
            if (starts[mid] <= s) lo = mid; else hi = mid;
        }
        recA[gbase[lo] + (s - starts[lo])] = staged[s];
    }
}

// ---------------- pass B: bucket -> 16 fine bins + degree/u0 ---------------
__global__ __launch_bounds__(TPB) void k_sub(
        const int* __restrict__ pos, const int2* __restrict__ recA,
        int2* __restrict__ recB,
        int* __restrict__ binStart, int* __restrict__ binEnd,
        const float* __restrict__ x, float* __restrict__ dis,
        float* __restrict__ d2, float* __restrict__ u0,
        int N, int CB,
        const float* __restrict__ W_orth,
        const float* __restrict__ W0, const float* __restrict__ b0,
        float* __restrict__ scal) {
    __shared__ float smem[6144];     // staged int2[2048] (16KB) + acc[2048] (8KB)
    __shared__ int h16[16], st16[17], run16[16], bh16[16], bst16[17];
    const int b = blockIdx.x, t = threadIdx.x;
    if (b == CB) { v_part(smem, W_orth, nullptr, W0, b0, scal, 3, 0, false); return; }
    int2* staged = (int2*)smem;                  // [2048]
    float* acc   = smem + 4096;                  // [2048]
    const int cnt = pos[b];
    const int2* rin = recA + ((size_t)b << CAPSH);
    int2* rout      = recB + ((size_t)b << CAPSH);
    for (int i = t; i < CSZ; i += TPB) acc[i] = 0.f;
    if (t < 16) h16[t] = 0;
    __syncthreads();
    // stream 1: fine-bin histogram + weighted degree
    for (int k = t; k < cnt; k += TPB) {
        int2 rc = rin[k];
        int cl = rc.x >> 18;                     // 11-bit local node
        atomicAdd(&h16[cl >> FSH], 1);
        atomicAdd(&acc[cl], __int_as_float(rc.y));
    }
    __syncthreads();
    if (t == 0) { int s = 0; for (int j = 0; j < 16; ++j) { st16[j] = s; s += h16[j]; } st16[16] = s; }
    __syncthreads();
    if (t < 16) {
        binStart[b * FBPB + t] = (b << CAPSH) + st16[t];
        binEnd  [b * FBPB + t] = (b << CAPSH) + st16[t + 1];
        run16[t] = st16[t];
    }
    // node epilogue: deg -> dis, d2, u0 = dis * x
    for (int i = t; i < CSZ; i += TPB) {
        int node = (b << CSH) + i;
        if (node < N) {
            float deg = 1.0f + acc[i];
            float ds = rsqrtf(deg);
            dis[node] = ds;
            d2[node]  = 1.0f / deg;
            u0[node]  = ds * x[node];
        }
    }
    __syncthreads();
    // stream 2: batches of 2048, LDS-sorted by fine bin, coalesced write-out
    for (int base = 0; base < cnt; base += 2048) {
        const int n = min(2048, cnt - base);
        if (t < 16) bh16[t] = 0;
        __syncthreads();
        for (int k = base + t; k < base + n; k += TPB)
            atomicAdd(&bh16[(rin[k].x >> 18) >> FSH], 1);
        __syncthreads();
        if (t == 0) { int s = 0; for (int j = 0; j < 16; ++j) { bst16[j] = s; s += bh16[j]; } bst16[16] = s; }
        __syncthreads();
        if (t < 16) bh16[t] = 0;                 // reuse as rank counter
        __syncthreads();
        for (int k = base + t; k < base + n; k += TPB) {
            int2 rc = rin[k];
            int cl = rc.x >> 18;
            int j = cl >> FSH;
            int r = atomicAdd(&bh16[j], 1);
            staged[bst16[j] + r] =
                make_int2((rc.x & 0x3FFFF) | ((cl & 127) << 18), rc.y);
        }
        __syncthreads();
        for (int s = t; s < n; s += TPB) {
            int lo = 0, hi = 16;
            while (hi - lo > 1) {
                int mid = (lo + hi) >> 1;
                if (bst16[mid] <= s) lo = mid; else hi = mid;
            }
            rout[run16[lo] + (s - bst16[lo])] = staged[s];
        }
        __syncthreads();
        if (t < 16) run16[t] += bh16[t];
        __syncthreads();
    }
}

// ---------------- propagation: one hop per launch --------------------------
// mode 1: c = s*u' + t*dis (combine channels after first hop)
// mode 2: out = u'/dis + b11 (final epilogue)
__global__ void k_gather(const int* __restrict__ binStart,
                         const int* __restrict__ binEnd,
                         const int2* __restrict__ rec,
                         const float* __restrict__ d2,
                         const float* __restrict__ pv, float* __restrict__ cv,
                         int N, int mode,
                         const float* __restrict__ scal,
                         const float* __restrict__ dis,
                         const float* __restrict__ b11, float* __restrict__ out) {
    const int fb = blockIdx.x, t = threadIdx.x;
    __shared__ float acc[128];
    if (t < 128) acc[t] = 0.f;
    __syncthreads();
    const int k0 = binStart[fb], k1 = binEnd[fb];
    for (int k = k0 + t; k < k1; k += TPB) {
        int2 rc = rec[k];
        atomicAdd(&acc[rc.x >> 18],
                  __int_as_float(rc.y) * pv[rc.x & 0x3FFFF]);
    }
    __syncthreads();
    if (t < 128) {
        int i = (fb << FSH) + t;      // fb*128 = bucket*2048 + fine*128
        if (i < N) {
            float up = d2[i] * (pv[i] + acc[t]);
            if (mode == 1)
                cv[i] = scal[0] * up + scal[1] * dis[i];
            else if (mode == 2)
                out[i] = up / dis[i] + b11[0];
            else
                cv[i] = up;
        }
    }
}

// ---------------- launch ----------------------------------------------------
extern "C" void kernel_launch(void* const* d_in, const int* in_sizes, int n_in,
                              void* d_out, int out_size, void* d_ws, size_t ws_size,
                              hipStream_t stream) {
    const float* x      = (const float*)d_in[0];
    const int*   ei     = (const int*)d_in[1];
    const float* w      = (const float*)d_in[2];
    const float* W0     = (const float*)d_in[3];
    const float* b0     = (const float*)d_in[4];
    const float* W_orth = (const float*)d_in[5];
    const float* W11    = (const float*)d_in[6];
    const float* b11    = (const float*)d_in[7];

    const int N = in_sizes[0];              // 200000 (< 2^18 for packing)
    const int E = in_sizes[2];              // 1200000
    const int CB = (N + CSZ - 1) >> CSH;    // 98 coarse buckets
    const int nchunk = (E + PE - 1) / PE;   // 293
    const size_t cap = (size_t)CB << CAPSH; // total record slots

    // workspace layout (8B-aligned first)
    char* ws = (char*)d_ws;
    int2*  recA     = (int2*)ws;   ws += cap * 8;
    int2*  recB     = (int2*)ws;   ws += cap * 8;
    float* uA       = (float*)ws;  ws += (size_t)N * 4;
    float* uB       = (float*)ws;  ws += (size_t)N * 4;
    float* dis      = (float*)ws;  ws += (size_t)N * 4;
    float* d2       = (float*)ws;  ws += (size_t)N * 4;
    int*   binStart = (int*)ws;    ws += (size_t)CB * FBPB * 4;
    int*   binEnd   = (int*)ws;    ws += (size_t)CB * FBPB * 4;
    int*   pos      = (int*)ws;    ws += 128 * 4;
    float* scal     = (float*)ws;  ws += 80 * 4;

    hipMemsetAsync(pos, 0, 128 * 4, stream);
    k_part<<<nchunk + 1, TPB, 0, stream>>>(ei, w, E, nchunk, CB, pos, recA,
                                           W_orth, W11, scal);
    k_sub<<<CB + 1, TPB, 0, stream>>>(pos, recA, recB, binStart, binEnd,
                                      x, dis, d2, uA, N, CB,
                                      W_orth, W0, b0, scal);

    float* prev = uA;
    float* cur  = uB;
    for (int it = 0; it < 12; ++it) {
        int mode = (it == 0) ? 1 : (it == 11 ? 2 : 0);
        k_gather<<<CB * FBPB, TPB, 0, stream>>>(binStart, binEnd, recB, d2,
                                                prev, cur, N, mode, scal, dis,
                                                b11, (float*)d_out);
        float* tmp = prev; prev = cur; cur = tmp;
    }
}

// Round 9
// 309.305 us; speedup vs baseline: 15.0435x; 1.0444x over previous
//
#include <hip/hip_runtime.h>
#include <hip/hip_bf16.h>

// Collapsed algebra:
//   out[i] = s * (A^12 x)[i] + t * (A^11 1)[i] + b11
//          = (A^11 (s * A x + t * 1))[i] + b11          <- single channel
// where A = D^{-1/2} (W + I) D^{-1/2} (self loops weight 1),
//   v = O_0 (O_1 (... (O_9 W11))),  O_k = Taylor_10(expm(Wk - Wk^T))
//   s = W0 . v,  t = b0 . v
// u-space: u = dis .* y  =>  u' = d2 .* (u + sum_e w_e u_src)
//
// R8: two-level radix build (coarse 2048-node buckets -> fine 128-node bins).
// R9: build kernels at TPB=1024 (4x waves: occupancy 3.8%->~50%), int4 edge
//     loads, staged-byte bin ids (no binary search), per-wave histograms.

#define TPB 256           // gather block size
#define CSH 11            // 2048 nodes per coarse bucket
#define CSZ 2048
#define CAPSH 14          // 16384 record slots per bucket
#define FSH 7             // 128 nodes per fine bin
#define FBPB 16           // fine bins per bucket
#define PE 4096           // edges per k_part block

// ---------------- v-chain part: single wave, no __syncthreads --------------
// smem: >= 4224 floats. st: st[0]=s, st[1]=t, st[2..66) carried state.
__device__ void v_part(float* __restrict__ smem,
                       const float* __restrict__ W_orth,
                       const float* __restrict__ W11,
                       const float* __restrict__ W0,
                       const float* __restrict__ b0,
                       float* __restrict__ st,
                       int khi, int klo, bool first) {
    const int l = threadIdx.x;
    if (l >= 64) return;                       // single wave
    float* S  = smem;                          // [64*65], +1 pad per row
    float* tl = smem + 4160;                   // [64]
    float u = first ? W11[l] : st[2 + l];
    for (int k = khi; k >= klo; --k) {
        const float* Wk = W_orth + (size_t)k * 4096;
        #pragma unroll 1
        for (int i = 0; i < 64; ++i)
            S[i * 65 + l] = Wk[i * 64 + l] - Wk[l * 64 + i];
        float term = u, acc = u;
        for (int t = 1; t <= 10; ++t) {
            tl[l] = term;
            float p = 0.f;
            #pragma unroll 16
            for (int j = 0; j < 64; ++j)
                p = fmaf(S[l * 65 + j], tl[j], p);   // tl[j]: LDS broadcast
            term = p / (float)t;
            acc += term;
        }
        u = acc;
    }
    if (klo == 0) {
        float a = W0[l] * u, b = b0[l] * u;
        #pragma unroll
        for (int off = 32; off; off >>= 1) {
            a += __shfl_down(a, off);
            b += __shfl_down(b, off);
        }
        if (l == 0) { st[0] = a; st[1] = b; }
    } else {
        st[2 + l] = u;
    }
}

// ---------------- pass A: edges -> 98 coarse buckets (coalesced) -----------
__global__ __launch_bounds__(1024) void k_part(
        const int* __restrict__ ei, const float* __restrict__ w,
        int E, int nchunk, int CB,
        int* __restrict__ pos, int2* __restrict__ recA,
        const float* __restrict__ W_orth,
        const float* __restrict__ W11, float* __restrict__ scal) {
    __shared__ float smem[9216];       // staged int2[4096] (32KB) + sb[4096] (4KB)
    __shared__ int hist[128], rank[128], gbase[128];
    __shared__ int sscan[128], starts[129];
    const int me = blockIdx.x, t = threadIdx.x;
    if (me == nchunk) { v_part(smem, W_orth, W11, nullptr, nullptr, scal, 9, 4, true); return; }
    int2* staged = (int2*)smem;
    unsigned char* sb = (unsigned char*)(smem + 8192);
    if (t < 128) { hist[t] = 0; rank[t] = 0; }
    __syncthreads();
    const int e0 = me * PE, e1 = min(E, e0 + PE);
    const int nE = e1 - e0;
    const int nv = nE >> 2;
    const int4*   cv4 = (const int4*)(ei + (size_t)E + e0);
    const int4*   sv4 = (const int4*)(ei + e0);
    const float4* wv4 = (const float4*)(w + e0);
    // histogram (int4 loads)
    for (int g = t; g < nv; g += 1024) {
        int4 c4 = cv4[g];
        atomicAdd(&hist[c4.x >> CSH], 1);
        atomicAdd(&hist[c4.y >> CSH], 1);
        atomicAdd(&hist[c4.z >> CSH], 1);
        atomicAdd(&hist[c4.w >> CSH], 1);
    }
    for (int e = e0 + (nv << 2) + t; e < e1; e += 1024)
        atomicAdd(&hist[ei[E + e] >> CSH], 1);
    __syncthreads();
    // exclusive scan of 128 buckets
    if (t < 128) sscan[t] = hist[t];
    __syncthreads();
    for (int o = 1; o < 128; o <<= 1) {
        int v = (t < 128 && t >= o) ? sscan[t - o] : 0;
        __syncthreads();
        if (t < 128) sscan[t] += v;
        __syncthreads();
    }
    if (t < 128) starts[t] = sscan[t] - hist[t];
    if (t == 127) starts[128] = sscan[127];
    // reserve global space per touched bucket
    if (t < CB && hist[t] > 0)
        gbase[t] = (t << CAPSH) + atomicAdd(&pos[t], hist[t]);
    __syncthreads();
    // rank + stage (record: src | c_low11 << 18, weight); bucket id -> sb
    for (int g = t; g < nv; g += 1024) {
        int4 s4 = sv4[g]; int4 c4 = cv4[g]; float4 w4 = wv4[g];
        int b, r, p;
        b = c4.x >> CSH; r = atomicAdd(&rank[b], 1); p = starts[b] + r;
        staged[p] = make_int2(s4.x | ((c4.x & (CSZ - 1)) << 18), __float_as_int(w4.x)); sb[p] = (unsigned char)b;
        b = c4.y >> CSH; r = atomicAdd(&rank[b], 1); p = starts[b] + r;
        staged[p] = make_int2(s4.y | ((c4.y & (CSZ - 1)) << 18), __float_as_int(w4.y)); sb[p] = (unsigned char)b;
        b = c4.z >> CSH; r = atomicAdd(&rank[b], 1); p = starts[b] + r;
        staged[p] = make_int2(s4.z | ((c4.z & (CSZ - 1)) << 18), __float_as_int(w4.z)); sb[p] = (unsigned char)b;
        b = c4.w >> CSH; r = atomicAdd(&rank[b], 1); p = starts[b] + r;
        staged[p] = make_int2(s4.w | ((c4.w & (CSZ - 1)) << 18), __float_as_int(w4.w)); sb[p] = (unsigned char)b;
    }
    for (int e = e0 + (nv << 2) + t; e < e1; e += 1024) {
        int src = ei[e], c = ei[E + e];
        int b = c >> CSH;
        int r = atomicAdd(&rank[b], 1);
        int p = starts[b] + r;
        staged[p] = make_int2(src | ((c & (CSZ - 1)) << 18), __float_as_int(w[e]));
        sb[p] = (unsigned char)b;
    }
    __syncthreads();
    // coalesced write-out using staged bucket ids
    for (int s = t; s < nE; s += 1024) {
        int b = sb[s];
        recA[gbase[b] + (s - starts[b])] = staged[s];
    }
}

// ---------------- pass B: bucket -> 16 fine bins + degree/u0 ---------------
__global__ __launch_bounds__(1024) void k_sub(
        const int* __restrict__ pos, const int2* __restrict__ recA,
        int2* __restrict__ recB,
        int* __restrict__ binStart, int* __restrict__ binEnd,
        const float* __restrict__ x, float* __restrict__ dis,
        float* __restrict__ d2, float* __restrict__ u0,
        int N, int CB,
        const float* __restrict__ W_orth,
        const float* __restrict__ W0, const float* __restrict__ b0,
        float* __restrict__ scal) {
    __shared__ float smem[6656];   // staged int2[2048] | acc[2048] | sb[2048B]
    __shared__ int hw[16][17];     // per-wave fine-bin histograms (padded)
    __shared__ int h16[16], st16[17], run16[16], rk16[16], bst16[17], bcnt[16];
    const int b = blockIdx.x, t = threadIdx.x;
    if (b == CB) { v_part(smem, W_orth, nullptr, W0, b0, scal, 3, 0, false); return; }
    int2* staged = (int2*)smem;                      // [2048]
    float* acc   = smem + 4096;                      // [2048]
    unsigned char* sb = (unsigned char*)(smem + 6144); // [2048]
    const int wid = t >> 6;
    const int cnt = pos[b];
    const int2* rin = recA + ((size_t)b << CAPSH);
    int2* rout      = recB + ((size_t)b << CAPSH);
    for (int i = t; i < CSZ; i += 1024) acc[i] = 0.f;
    if (t < 272) ((int*)hw)[t] = 0;
    __syncthreads();
    // stream 1: fine-bin histogram (per-wave privatized) + weighted degree
    for (int k = t; k < cnt; k += 1024) {
        int2 rc = rin[k];
        int cl = rc.x >> 18;                         // 11-bit local node
        atomicAdd(&hw[wid][cl >> FSH], 1);
        atomicAdd(&acc[cl], __int_as_float(rc.y));
    }
    __syncthreads();
    if (t < 16) { int s = 0; for (int q = 0; q < 16; ++q) s += hw[q][t]; h16[t] = s; }
    __syncthreads();
    if (t == 0) { int s = 0; for (int j = 0; j < 16; ++j) { st16[j] = s; s += h16[j]; } st16[16] = s; }
    __syncthreads();
    if (t < 16) {
        binStart[b * FBPB + t] = (b << CAPSH) + st16[t];
        binEnd  [b * FBPB + t] = (b << CAPSH) + st16[t + 1];
        run16[t] = st16[t];
    }
    // node epilogue: deg -> dis, d2, u0 = dis * x
    for (int i = t; i < CSZ; i += 1024) {
        int node = (b << CSH) + i;
        if (node < N) {
            float deg = 1.0f + acc[i];
            float ds = rsqrtf(deg);
            dis[node] = ds;
            d2[node]  = 1.0f / deg;
            u0[node]  = ds * x[node];
        }
    }
    __syncthreads();
    // stream 2: batches of 2048, LDS-sorted by fine bin, coalesced write-out
    for (int base = 0; base < cnt; base += 2048) {
        const int n = min(2048, cnt - base);
        if (t < 272) ((int*)hw)[t] = 0;
        __syncthreads();
        for (int k = base + t; k < base + n; k += 1024)
            atomicAdd(&hw[wid][(rin[k].x >> 18) >> FSH], 1);
        __syncthreads();
        if (t < 16) { int s = 0; for (int q = 0; q < 16; ++q) s += hw[q][t]; bcnt[t] = s; rk16[t] = 0; }
        __syncthreads();
        if (t == 0) { int s = 0; for (int j = 0; j < 16; ++j) { bst16[j] = s; s += bcnt[j]; } bst16[16] = s; }
        __syncthreads();
        for (int k = base + t; k < base + n; k += 1024) {
            int2 rc = rin[k];
            int cl = rc.x >> 18;
            int j = cl >> FSH;
            int r = atomicAdd(&rk16[j], 1);
            int p = bst16[j] + r;
            staged[p] = make_int2((rc.x & 0x3FFFF) | ((cl & 127) << 18), rc.y);
            sb[p] = (unsigned char)j;
        }
        __syncthreads();
        for (int s = t; s < n; s += 1024) {
            int j = sb[s];
            rout[run16[j] + (s - bst16[j])] = staged[s];
        }
        __syncthreads();
        if (t < 16) run16[t] += bcnt[t];
        __syncthreads();
    }
}

// ---------------- propagation: one hop per launch --------------------------
// mode 1: c = s*u' + t*dis (combine channels after first hop)
// mode 2: out = u'/dis + b11 (final epilogue)
__global__ void k_gather(const int* __restrict__ binStart,
                         const int* __restrict__ binEnd,
                         const int2* __restrict__ rec,
                         const float* __restrict__ d2,
                         const float* __restrict__ pv, float* __restrict__ cv,
                         int N, int mode,
                         const float* __restrict__ scal,
                         const float* __restrict__ dis,
                         const float* __restrict__ b11, float* __restrict__ out) {
    const int fb = blockIdx.x, t = threadIdx.x;
    __shared__ float acc[128];
    if (t < 128) acc[t] = 0.f;
    __syncthreads();
    const int k0 = binStart[fb], k1 = binEnd[fb];
    for (int k = k0 + t; k < k1; k += TPB) {
        int2 rc = rec[k];
        atomicAdd(&acc[rc.x >> 18],
                  __int_as_float(rc.y) * pv[rc.x & 0x3FFFF]);
    }
    __syncthreads();
    if (t < 128) {
        int i = (fb << FSH) + t;      // fb*128 = bucket*2048 + fine*128
        if (i < N) {
            float up = d2[i] * (pv[i] + acc[t]);
            if (mode == 1)
                cv[i] = scal[0] * up + scal[1] * dis[i];
            else if (mode == 2)
                out[i] = up / dis[i] + b11[0];
            else
                cv[i] = up;
        }
    }
}

// ---------------- launch ----------------------------------------------------
extern "C" void kernel_launch(void* const* d_in, const int* in_sizes, int n_in,
                              void* d_out, int out_size, void* d_ws, size_t ws_size,
                              hipStream_t stream) {
    const float* x      = (const float*)d_in[0];
    const int*   ei     = (const int*)d_in[1];
    const float* w      = (const float*)d_in[2];
    const float* W0     = (const float*)d_in[3];
    const float* b0     = (const float*)d_in[4];
    const float* W_orth = (const float*)d_in[5];
    const float* W11    = (const float*)d_in[6];
    const float* b11    = (const float*)d_in[7];

    const int N = in_sizes[0];              // 200000 (< 2^18 for packing)
    const int E = in_sizes[2];              // 1200000
    const int CB = (N + CSZ - 1) >> CSH;    // 98 coarse buckets
    const int nchunk = (E + PE - 1) / PE;   // 293
    const size_t cap = (size_t)CB << CAPSH; // total record slots

    // workspace layout (8B-aligned first)
    char* ws = (char*)d_ws;
    int2*  recA     = (int2*)ws;   ws += cap * 8;
    int2*  recB     = (int2*)ws;   ws += cap * 8;
    float* uA       = (float*)ws;  ws += (size_t)N * 4;
    float* uB       = (float*)ws;  ws += (size_t)N * 4;
    float* dis      = (float*)ws;  ws += (size_t)N * 4;
    float* d2       = (float*)ws;  ws += (size_t)N * 4;
    int*   binStart = (int*)ws;    ws += (size_t)CB * FBPB * 4;
    int*   binEnd   = (int*)ws;    ws += (size_t)CB * FBPB * 4;
    int*   pos      = (int*)ws;    ws += 128 * 4;
    float* scal     = (float*)ws;  ws += 80 * 4;

    hipMemsetAsync(pos, 0, 128 * 4, stream);
    k_part<<<nchunk + 1, 1024, 0, stream>>>(ei, w, E, nchunk, CB, pos, recA,
                                            W_orth, W11, scal);
    k_sub<<<CB + 1, 1024, 0, stream>>>(pos, recA, recB, binStart, binEnd,
                                       x, dis, d2, uA, N, CB,
                                       W_orth, W0, b0, scal);

    float* prev = uA;
    float* cur  = uB;
    for (int it = 0; it < 12; ++it) {
        int mode = (it == 0) ? 1 : (it == 11 ? 2 : 0);
        k_gather<<<CB * FBPB, TPB, 0, stream>>>(binStart, binEnd, recB, d2,
                                                prev, cur, N, mode, scal, dis,
                                                b11, (float*)d_out);
        float* tmp = prev; prev = cur; cur = tmp;
    }
}